// Round 8
// baseline (455.093 us; speedup 1.0000x reference)
//
#include <hip/hip_runtime.h>
#include <hip/hip_bf16.h>

#define BB 8
#define NN 1024
#define EE 16384
#define FF 96
#define FE 32
#define NH 12
#define DD 8
#define KM 224   // 2F + Fe
#define KX 192   // 2F
#define TE 64    // rows per GEMM tile
#define BK 32    // K chunk

__device__ __forceinline__ float gelu_erf(float x){
    return 0.5f * x * (1.0f + erff(x * 0.70710678118654752f));
}

__device__ __forceinline__ int load_idx(const int* __restrict__ p, int i){
    int v = p[i];
    if (!((unsigned)v < 1024u)) v = (int)__int_as_float(v);
    return min(max(v, 0), NN-1);
}

// ---------------- CSR build: histogram ----------------
__global__ __launch_bounds__(256) void hist_kernel(
    const int* __restrict__ edges, int* __restrict__ cnt)
{
    const int i = blockIdx.x*blockDim.x + threadIdx.x;   // b*E + e
    if (i < BB*EE){
        const int b = i >> 14;
        const int dst = load_idx(edges, 2*i+1);
        atomicAdd(&cnt[b*NN + dst], 1);
    }
}

// ---------------- CSR build: per-batch exclusive scan (N=1024) ----------------
__global__ __launch_bounds__(1024) void scan_kernel(
    const int* __restrict__ cnt, int* __restrict__ rowstart, int* __restrict__ cursor)
{
    const int b = blockIdx.x;
    const int t = threadIdx.x;
    __shared__ int s[NN];
    const int v = cnt[b*NN + t];
    s[t] = v;
    __syncthreads();
    for (int off = 1; off < NN; off <<= 1){
        int u = (t >= off) ? s[t-off] : 0;
        __syncthreads();
        s[t] += u;
        __syncthreads();
    }
    const int ex = s[t] - v + b*EE;     // exclusive, offset by batch base
    rowstart[b*NN + t] = ex;
    cursor[b*NN + t]   = ex;
}

// ---------------- CSR build: scatter edge ids ----------------
__global__ __launch_bounds__(256) void scatter_kernel(
    const int* __restrict__ edges, int* __restrict__ cursor, int* __restrict__ elist)
{
    const int i = blockIdx.x*blockDim.x + threadIdx.x;   // global edge id
    if (i < BB*EE){
        const int b = i >> 14;
        const int dst = load_idx(edges, 2*i+1);
        const int pos = atomicAdd(&cursor[b*NN + dst], 1);
        elist[pos] = i;
    }
}

// ---------------- Kernel 1: edge messages (tiled GEMM + fused epilogue) ----
__global__ __launch_bounds__(256) void edge_msg_kernel(
    const float* __restrict__ nodes, const float* __restrict__ ef,
    const int*  __restrict__ edges, const float* __restrict__ ew,
    const float* __restrict__ Wm, const float* __restrict__ bm,
    const float* __restrict__ gm, const float* __restrict__ betam,
    float* __restrict__ wm_out)
{
    const int bid = blockIdx.x;
    const int tid = threadIdx.x;
    const int tx  = tid & 15;
    const int ty  = tid >> 4;
    const int be0 = bid * TE;
    const int b   = be0 >> 14;

    __shared__ float Xs[TE][BK+4];
    __shared__ float Ws[BK][FF];
    __shared__ int   eidx[TE*2];
    __shared__ float ewS[TE];
    __shared__ float bmS[FF], gmS[FF], betamS[FF];

    if (tid < TE*2){
        int v = edges[(size_t)be0*2 + tid];
        if (!((unsigned)v < 1024u)) v = (int)__int_as_float(v);
        eidx[tid] = min(max(v, 0), NN-1);
    }
    if (tid < TE) ewS[tid] = ew[be0 + tid];
    if (tid < FF){ bmS[tid] = bm[tid]; gmS[tid] = gm[tid]; betamS[tid] = betam[tid]; }

    float acc[4][6];
    #pragma unroll
    for (int a=0;a<4;++a)
        #pragma unroll
        for (int c=0;c<6;++c) acc[a][c] = 0.f;

    const int e_st = tid >> 2;
    const int kk0  = (tid & 3) * 8;

    __syncthreads();

    for (int c = 0; c < 7; ++c){
        const int kbase = c * BK;
        __syncthreads();
        {
            const float4* src = (const float4*)(Wm + (size_t)kbase*FF);
            float4* dst = (float4*)&Ws[0][0];
            dst[tid      ] = src[tid      ];
            dst[tid + 256] = src[tid + 256];
            dst[tid + 512] = src[tid + 512];
        }
        {
            const float* rp;
            if (c < 3)      rp = nodes + (size_t)(b*NN + eidx[2*e_st  ])*FF + kbase;
            else if (c < 6) rp = nodes + (size_t)(b*NN + eidx[2*e_st+1])*FF + (kbase - FF);
            else            rp = ef + (size_t)(be0 + e_st)*FE;
            *(float4*)&Xs[e_st][kk0    ] = *(const float4*)(rp + kk0);
            *(float4*)&Xs[e_st][kk0 + 4] = *(const float4*)(rp + kk0 + 4);
        }
        __syncthreads();
        #pragma unroll 4
        for (int kk = 0; kk < BK; ++kk){
            float2 w01 = *(const float2*)&Ws[kk][6*tx    ];
            float2 w23 = *(const float2*)&Ws[kk][6*tx + 2];
            float2 w45 = *(const float2*)&Ws[kk][6*tx + 4];
            float xv[4];
            #pragma unroll
            for (int ei=0; ei<4; ++ei) xv[ei] = Xs[ty + 16*ei][kk];
            #pragma unroll
            for (int ei=0; ei<4; ++ei){
                acc[ei][0] += xv[ei]*w01.x;  acc[ei][1] += xv[ei]*w01.y;
                acc[ei][2] += xv[ei]*w23.x;  acc[ei][3] += xv[ei]*w23.y;
                acc[ei][4] += xv[ei]*w45.x;  acc[ei][5] += xv[ei]*w45.y;
            }
        }
    }

    #pragma unroll
    for (int ei = 0; ei < 4; ++ei){
        const int el = ty + 16*ei;
        float h[6]; float psum = 0.f;
        #pragma unroll
        for (int jj=0; jj<6; ++jj){
            h[jj] = gelu_erf(acc[ei][jj] + bmS[6*tx + jj]);
            psum += h[jj];
        }
        #pragma unroll
        for (int m=1; m<16; m<<=1) psum += __shfl_xor(psum, m, 16);
        const float mu = psum * (1.f/FF);
        float vsum = 0.f;
        #pragma unroll
        for (int jj=0; jj<6; ++jj){ float d = h[jj]-mu; vsum += d*d; }
        #pragma unroll
        for (int m=1; m<16; m<<=1) vsum += __shfl_xor(vsum, m, 16);
        const float rstd = rsqrtf(vsum*(1.f/FF) + 1e-3f);

        const float w = ewS[el];
        float* __restrict__ wrow = wm_out + (size_t)(be0 + el)*FF + 6*tx;
        #pragma unroll
        for (int jj=0; jj<6; ++jj)
            wrow[jj] = ((h[jj]-mu)*rstd*gmS[6*tx+jj] + betamS[6*tx+jj]) * w;
    }
}

// ---------------- Kernel 1b: CSR gather -> agg ----------------
__global__ __launch_bounds__(96) void gather_kernel(
    const float* __restrict__ wm_out, const float* __restrict__ ed,
    const int* __restrict__ elist, const int* __restrict__ rowstart,
    const int* __restrict__ cnt, float* __restrict__ agg)
{
    const int bn = blockIdx.x;       // b*N + n
    const int t  = threadIdx.x;      // 96
    const int beg = rowstart[bn];
    const int num = cnt[bn];
    float sum = 0.f;
    for (int i = 0; i < num; ++i){
        const int be = elist[beg + i];
        const float coeff = ed[2*(size_t)be + 1];
        sum += wm_out[(size_t)be*FF + t] * coeff;
    }
    agg[(size_t)bn*FF + t] = sum;
}

// ---------------- Kernel 2: QKVG projections (tiled GEMM) ----------------
__global__ __launch_bounds__(256) void qkvg_kernel(
    const float* __restrict__ nodes, const float* __restrict__ agg,
    const float* __restrict__ Wq, const float* __restrict__ bq,
    const float* __restrict__ Wk, const float* __restrict__ bk,
    const float* __restrict__ Wv, const float* __restrict__ bv,
    const float* __restrict__ Wg, const float* __restrict__ bg,
    float* __restrict__ qo, float* __restrict__ ko,
    float* __restrict__ vo, float* __restrict__ go)
{
    const int rt  = blockIdx.x;          // 128 row tiles
    const int m   = blockIdx.y;          // 0..3
    const int tid = threadIdx.x;
    const int tx  = tid & 15;
    const int ty  = tid >> 4;
    const int r0  = rt * TE;

    const float* W    = (m==0)?Wq:(m==1)?Wk:(m==2)?Wv:Wg;
    const float* bias = (m==0)?bq:(m==1)?bk:(m==2)?bv:bg;
    float* out        = (m==0)?qo:(m==1)?ko:(m==2)?vo:go;

    __shared__ float Xs[TE][BK+4];
    __shared__ float Ws[BK][FF];
    __shared__ float bS[FF];
    if (tid < FF) bS[tid] = bias[tid];

    float acc[4][6];
    #pragma unroll
    for (int a=0;a<4;++a)
        #pragma unroll
        for (int c=0;c<6;++c) acc[a][c] = 0.f;

    const int e_st = tid >> 2;
    const int kk0  = (tid & 3) * 8;

    for (int c = 0; c < 6; ++c){
        __syncthreads();
        {
            const float4* src = (const float4*)(W + (size_t)c*BK*FF);
            float4* dst = (float4*)&Ws[0][0];
            dst[tid      ] = src[tid      ];
            dst[tid + 256] = src[tid + 256];
            dst[tid + 512] = src[tid + 512];
        }
        {
            const float* rp = (c < 3)
                ? nodes + (size_t)(r0 + e_st)*FF + c*BK
                : agg   + (size_t)(r0 + e_st)*FF + (c-3)*BK;
            *(float4*)&Xs[e_st][kk0    ] = *(const float4*)(rp + kk0);
            *(float4*)&Xs[e_st][kk0 + 4] = *(const float4*)(rp + kk0 + 4);
        }
        __syncthreads();
        #pragma unroll 4
        for (int kk = 0; kk < BK; ++kk){
            float2 w01 = *(const float2*)&Ws[kk][6*tx    ];
            float2 w23 = *(const float2*)&Ws[kk][6*tx + 2];
            float2 w45 = *(const float2*)&Ws[kk][6*tx + 4];
            float xv[4];
            #pragma unroll
            for (int ei=0; ei<4; ++ei) xv[ei] = Xs[ty + 16*ei][kk];
            #pragma unroll
            for (int ei=0; ei<4; ++ei){
                acc[ei][0] += xv[ei]*w01.x;  acc[ei][1] += xv[ei]*w01.y;
                acc[ei][2] += xv[ei]*w23.x;  acc[ei][3] += xv[ei]*w23.y;
                acc[ei][4] += xv[ei]*w45.x;  acc[ei][5] += xv[ei]*w45.y;
            }
        }
    }

    #pragma unroll
    for (int ei = 0; ei < 4; ++ei){
        const int row = r0 + ty + 16*ei;
        float* __restrict__ orow = out + (size_t)row*FF + 6*tx;
        #pragma unroll
        for (int jj=0; jj<6; ++jj) orow[jj] = acc[ei][jj] + bS[6*tx + jj];
    }
}

// ---------------- Kernel 3: gated attention (K-split flash) ----------------
// block = 256 thr = 4 waves per (b, h, 64-row q-tile). Wave w handles keys
// [256w, 256w+256) for all 64 q-rows (one row per lane); partials merged in
// LDS. att MAY alias g: merge-phase reads g then writes att at the same
// address from the same thread.
__global__ __launch_bounds__(256) void attn_kernel(
    const float* __restrict__ q, const float* __restrict__ k,
    const float* __restrict__ v, const float* g,
    float* att)
{
    const int blk = blockIdx.x;
    const int qt = blk & 15;              // N/64 = 16 tiles
    const int h  = (blk >> 4) % NH;
    const int b  = blk / (16*NH);
    const int tid  = threadIdx.x;
    const int lane = tid & 63;
    const int w    = tid >> 6;            // 0..3 (k-split)
    const int qrow = qt*64 + lane;
    const size_t base = (size_t)(b*NN)*FF + h*DD;

    float qr[DD];
    const float* qp = q + base + (size_t)qrow*FF;
    #pragma unroll
    for (int i=0;i<DD;++i) qr[i] = qp[i] * 0.35355339059327373f;   // 1/sqrt(8)

    float m = -1e30f, l = 0.f, o[DD];
    #pragma unroll
    for (int i=0;i<DD;++i) o[i] = 0.f;

    const int kc0 = w * 256;
    const float* kp = k + base + (size_t)kc0*FF;
    const float* vp = v + base + (size_t)kc0*FF;
    for (int j = 0; j < 256; ++j){
        float4 k0 = *(const float4*)(kp);
        float4 k1 = *(const float4*)(kp + 4);
        float4 v0 = *(const float4*)(vp);
        float4 v1 = *(const float4*)(vp + 4);
        kp += FF; vp += FF;
        float s = qr[0]*k0.x + qr[1]*k0.y + qr[2]*k0.z + qr[3]*k0.w
                + qr[4]*k1.x + qr[5]*k1.y + qr[6]*k1.z + qr[7]*k1.w;
        float mn = fmaxf(m, s);
        float c = __expf(m - mn);
        float p = __expf(s - mn);
        l = l*c + p;
        o[0] = o[0]*c + p*v0.x;  o[1] = o[1]*c + p*v0.y;
        o[2] = o[2]*c + p*v0.z;  o[3] = o[3]*c + p*v0.w;
        o[4] = o[4]*c + p*v1.x;  o[5] = o[5]*c + p*v1.y;
        o[6] = o[6]*c + p*v1.z;  o[7] = o[7]*c + p*v1.w;
        m = mn;
    }

    __shared__ float mS[4][64], lS[4][64], oS[4][64][DD+1];
    mS[w][lane] = m;
    lS[w][lane] = l;
    #pragma unroll
    for (int i=0;i<DD;++i) oS[w][lane][i] = o[i];
    __syncthreads();

    if (tid < 64){
        float M = mS[0][lane];
        #pragma unroll
        for (int w2=1; w2<4; ++w2) M = fmaxf(M, mS[w2][lane]);
        float L = 0.f, O[DD];
        #pragma unroll
        for (int i=0;i<DD;++i) O[i] = 0.f;
        #pragma unroll
        for (int w2=0; w2<4; ++w2){
            const float c = __expf(mS[w2][lane] - M);
            L += lS[w2][lane] * c;
            #pragma unroll
            for (int i=0;i<DD;++i) O[i] += oS[w2][lane][i] * c;
        }
        const float inv = 1.f / L;
        const float* gp = g + base + (size_t)qrow*FF;
        float* ap = att + base + (size_t)qrow*FF;
        #pragma unroll
        for (int i=0;i<DD;++i){
            const float gate = 1.f/(1.f + __expf(-gp[i]));
            ap[i] = O[i]*inv*gate;
        }
    }
}

// ---------------- Kernel 4: output projection (tiled GEMM + GELU + LN) ----
__global__ __launch_bounds__(256) void out_kernel(
    const float* __restrict__ att, const float* __restrict__ Wo, const float* __restrict__ bo,
    const float* __restrict__ gu, const float* __restrict__ betau,
    float* __restrict__ out0)
{
    const int rt  = blockIdx.x;
    const int tid = threadIdx.x;
    const int tx  = tid & 15;
    const int ty  = tid >> 4;
    const int r0  = rt * TE;

    __shared__ float Xs[TE][BK+4];
    __shared__ float Ws[BK][FF];
    __shared__ float boS[FF], guS[FF], beS[FF];
    if (tid < FF){ boS[tid] = bo[tid]; guS[tid] = gu[tid]; beS[tid] = betau[tid]; }

    float acc[4][6];
    #pragma unroll
    for (int a=0;a<4;++a)
        #pragma unroll
        for (int c=0;c<6;++c) acc[a][c] = 0.f;

    const int e_st = tid >> 2;
    const int kk0  = (tid & 3) * 8;

    for (int c = 0; c < 3; ++c){
        __syncthreads();
        {
            const float4* src = (const float4*)(Wo + (size_t)c*BK*FF);
            float4* dst = (float4*)&Ws[0][0];
            dst[tid      ] = src[tid      ];
            dst[tid + 256] = src[tid + 256];
            dst[tid + 512] = src[tid + 512];
        }
        {
            const float* rp = att + (size_t)(r0 + e_st)*FF + c*BK;
            *(float4*)&Xs[e_st][kk0    ] = *(const float4*)(rp + kk0);
            *(float4*)&Xs[e_st][kk0 + 4] = *(const float4*)(rp + kk0 + 4);
        }
        __syncthreads();
        #pragma unroll 4
        for (int kk = 0; kk < BK; ++kk){
            float2 w01 = *(const float2*)&Ws[kk][6*tx    ];
            float2 w23 = *(const float2*)&Ws[kk][6*tx + 2];
            float2 w45 = *(const float2*)&Ws[kk][6*tx + 4];
            float xv[4];
            #pragma unroll
            for (int ei=0; ei<4; ++ei) xv[ei] = Xs[ty + 16*ei][kk];
            #pragma unroll
            for (int ei=0; ei<4; ++ei){
                acc[ei][0] += xv[ei]*w01.x;  acc[ei][1] += xv[ei]*w01.y;
                acc[ei][2] += xv[ei]*w23.x;  acc[ei][3] += xv[ei]*w23.y;
                acc[ei][4] += xv[ei]*w45.x;  acc[ei][5] += xv[ei]*w45.y;
            }
        }
    }

    #pragma unroll
    for (int ei = 0; ei < 4; ++ei){
        const int row = r0 + ty + 16*ei;
        float h[6]; float psum = 0.f;
        #pragma unroll
        for (int jj=0; jj<6; ++jj){
            h[jj] = gelu_erf(acc[ei][jj] + boS[6*tx + jj]);
            psum += h[jj];
        }
        #pragma unroll
        for (int m=1; m<16; m<<=1) psum += __shfl_xor(psum, m, 16);
        const float mu = psum * (1.f/FF);
        float vsum = 0.f;
        #pragma unroll
        for (int jj=0; jj<6; ++jj){ float d = h[jj]-mu; vsum += d*d; }
        #pragma unroll
        for (int m=1; m<16; m<<=1) vsum += __shfl_xor(vsum, m, 16);
        const float rstd = rsqrtf(vsum*(1.f/FF) + 1e-3f);
        float* __restrict__ orow = out0 + (size_t)row*FF + 6*tx;
        #pragma unroll
        for (int jj=0; jj<6; ++jj)
            orow[jj] = (h[jj]-mu)*rstd*guS[6*tx+jj] + beS[6*tx+jj];
    }
}

// ---------------- Kernel 5: pass-through outputs (fp32) ----------------
__global__ void passthrough_kernel(const int* __restrict__ edges,
    const float* __restrict__ ew, const float* __restrict__ ed,
    float* __restrict__ o_edges, float* __restrict__ o_ew, float* __restrict__ o_ed)
{
    const int i = blockIdx.x*blockDim.x + threadIdx.x;
    const int NE2 = BB*EE*2;
    const int NW  = BB*EE;
    if (i < NE2)                 o_edges[i] = (float)load_idx(edges, i);
    else if (i < NE2+NW)         o_ew[i-NE2] = ew[i-NE2];
    else if (i < NE2+NW+NE2)     o_ed[i-NE2-NW] = ed[i-NE2-NW];
}

extern "C" void kernel_launch(void* const* d_in, const int* in_sizes, int n_in,
                              void* d_out, int out_size, void* d_ws, size_t ws_size,
                              hipStream_t stream) {
    // ---- adaptive input mapping by element count (dict-order tiebreak) ----
    int i_nodes=-1, i_ef=-1, i_edges=-1, i_ed=-1, i_ew=-1, i_Wm=-1, i_Wo=-1;
    int i_W4[4]; int nW4=0;
    int i_v96[10]; int nv96=0;
    for (int i = 0; i < n_in; ++i){
        const int s = in_sizes[i];
        if      (s == 786432)  i_nodes = i;
        else if (s == 4194304) i_ef = i;
        else if (s == 262144)  { if (i_edges < 0) i_edges = i; else i_ed = i; }
        else if (s == 131072)  i_ew = i;
        else if (s == 21504)   i_Wm = i;
        else if (s == 18432)   { if (nW4 < 4) i_W4[nW4++] = i; }
        else if (s == 9216)    i_Wo = i;
        else if (s == 96)      { if (nv96 < 10) i_v96[nv96++] = i; }
    }
    const float* nodes = (const float*)d_in[i_nodes];
    const float* ef    = (const float*)d_in[i_ef];
    const int*   edges = (const int*)d_in[i_edges];
    const float* ew    = (const float*)d_in[i_ew];
    const float* ed    = (const float*)d_in[i_ed];
    const float* Wm = (const float*)d_in[i_Wm];
    const float* Wq = (const float*)d_in[i_W4[0]];
    const float* Wk = (const float*)d_in[i_W4[1]];
    const float* Wv = (const float*)d_in[i_W4[2]];
    const float* Wg = (const float*)d_in[i_W4[3]];
    const float* Wo = (const float*)d_in[i_Wo];
    const float* bm    = (const float*)d_in[i_v96[0]];
    const float* gm    = (const float*)d_in[i_v96[1]];
    const float* betam = (const float*)d_in[i_v96[2]];
    const float* bq    = (const float*)d_in[i_v96[3]];
    const float* bk    = (const float*)d_in[i_v96[4]];
    const float* bv    = (const float*)d_in[i_v96[5]];
    const float* bg    = (const float*)d_in[i_v96[6]];
    const float* bo    = (const float*)d_in[i_v96[7]];
    const float* gu    = (const float*)d_in[i_v96[8]];
    const float* betau = (const float*)d_in[i_v96[9]];

    // ---- output layout: fp32, reference return order ----
    float* outp = (float*)d_out;
    const size_t ROWS  = (size_t)BB*NN*FF;     // 786432
    const size_t WMSZ  = (size_t)BB*EE*FF;     // 12582912
    const size_t NE2   = (size_t)BB*EE*2;      // 262144
    const size_t NW    = (size_t)BB*EE;        // 131072
    float* out_un    = outp;
    float* out_wm    = outp + ROWS;
    float* out_edges = outp + ROWS + WMSZ;
    float* out_ew    = outp + ROWS + WMSZ + NE2;
    float* out_ed    = outp + ROWS + WMSZ + NE2 + NW;

    // ---- workspace layout ----
    float* ws  = (float*)d_ws;
    float* agg = ws;
    float* qo  = ws + 1*ROWS;
    float* ko  = ws + 2*ROWS;
    float* vo  = ws + 3*ROWS;
    float* go  = ws + 4*ROWS;       // att aliases go (safe: same-thread RMW)
    float* att = go;
    int* ints      = (int*)(ws + 5*ROWS);
    int* cnt       = ints;                    // B*N
    int* rowstart  = ints + BB*NN;            // B*N
    int* cursor    = ints + 2*BB*NN;          // B*N
    int* elist     = ints + 3*BB*NN;          // B*E

    hipMemsetAsync(cnt, 0, BB*NN*sizeof(int), stream);

    // CSR build (independent of GEMM)
    hist_kernel<<<(BB*EE+255)/256, 256, 0, stream>>>(edges, cnt);
    scan_kernel<<<BB, NN, 0, stream>>>(cnt, rowstart, cursor);
    scatter_kernel<<<(BB*EE+255)/256, 256, 0, stream>>>(edges, cursor, elist);

    // edge messages (writes wm only; no atomics)
    edge_msg_kernel<<<(BB*EE)/TE, 256, 0, stream>>>(nodes, ef, edges, ew,
                                               Wm, bm, gm, betam, out_wm);
    // CSR gather -> agg
    gather_kernel<<<BB*NN, 96, 0, stream>>>(out_wm, ed, elist, rowstart, cnt, agg);

    dim3 qgrid((BB*NN)/TE, 4);
    qkvg_kernel<<<qgrid, 256, 0, stream>>>(nodes, agg, Wq, bq, Wk, bk, Wv, bv,
                                           Wg, bg, qo, ko, vo, go);
    attn_kernel<<<BB*NH*16, 256, 0, stream>>>(qo, ko, vo, go, att);
    out_kernel<<<(BB*NN)/TE, 256, 0, stream>>>(att, Wo, bo, gu, betau, out_un);

    const int npass = (int)(NE2 + NW + NE2);
    passthrough_kernel<<<(npass+255)/256, 256, 0, stream>>>(edges, ew, ed,
                                               out_edges, out_ew, out_ed);
}

// Round 9
// 454.877 us; speedup vs baseline: 1.0005x; 1.0005x over previous
//
#include <hip/hip_runtime.h>
#include <hip/hip_bf16.h>

#define BB 8
#define NN 1024
#define EE 16384
#define FF 96
#define FE 32
#define NH 12
#define DD 8
#define KM 224   // 2F + Fe
#define KX 192   // 2F
#define TE 64    // rows per GEMM tile
#define BK 32    // K chunk

__device__ __forceinline__ float gelu_erf(float x){
    return 0.5f * x * (1.0f + erff(x * 0.70710678118654752f));
}

__device__ __forceinline__ int load_idx(const int* __restrict__ p, int i){
    int v = p[i];
    if (!((unsigned)v < 1024u)) v = (int)__int_as_float(v);
    return min(max(v, 0), NN-1);
}

// ---------------- CSR build: histogram ----------------
__global__ __launch_bounds__(256) void hist_kernel(
    const int* __restrict__ edges, int* __restrict__ cnt)
{
    const int i = blockIdx.x*blockDim.x + threadIdx.x;   // b*E + e
    if (i < BB*EE){
        const int b = i >> 14;
        const int dst = load_idx(edges, 2*i+1);
        atomicAdd(&cnt[b*NN + dst], 1);
    }
}

// ---------------- CSR build: per-batch exclusive scan (N=1024) ----------------
__global__ __launch_bounds__(1024) void scan_kernel(
    const int* __restrict__ cnt, int* __restrict__ rowstart, int* __restrict__ cursor)
{
    const int b = blockIdx.x;
    const int t = threadIdx.x;
    __shared__ int s[NN];
    const int v = cnt[b*NN + t];
    s[t] = v;
    __syncthreads();
    for (int off = 1; off < NN; off <<= 1){
        int u = (t >= off) ? s[t-off] : 0;
        __syncthreads();
        s[t] += u;
        __syncthreads();
    }
    const int ex = s[t] - v + b*EE;     // exclusive, offset by batch base
    rowstart[b*NN + t] = ex;
    cursor[b*NN + t]   = ex;
}

// ---------------- CSR build: scatter edge ids ----------------
__global__ __launch_bounds__(256) void scatter_kernel(
    const int* __restrict__ edges, int* __restrict__ cursor, int* __restrict__ elist)
{
    const int i = blockIdx.x*blockDim.x + threadIdx.x;   // global edge id
    if (i < BB*EE){
        const int b = i >> 14;
        const int dst = load_idx(edges, 2*i+1);
        const int pos = atomicAdd(&cursor[b*NN + dst], 1);
        elist[pos] = i;
    }
}

// ---------------- Kernel 1: edge messages (tiled GEMM + fused epilogue) ----
__global__ __launch_bounds__(256) void edge_msg_kernel(
    const float* __restrict__ nodes, const float* __restrict__ ef,
    const int*  __restrict__ edges, const float* __restrict__ ew,
    const float* __restrict__ Wm, const float* __restrict__ bm,
    const float* __restrict__ gm, const float* __restrict__ betam,
    float* __restrict__ wm_out)
{
    const int bid = blockIdx.x;
    const int tid = threadIdx.x;
    const int tx  = tid & 15;
    const int ty  = tid >> 4;
    const int be0 = bid * TE;
    const int b   = be0 >> 14;

    __shared__ float Xs[TE][BK+4];
    __shared__ float Ws[BK][FF];
    __shared__ int   eidx[TE*2];
    __shared__ float ewS[TE];
    __shared__ float bmS[FF], gmS[FF], betamS[FF];

    if (tid < TE*2){
        int v = edges[(size_t)be0*2 + tid];
        if (!((unsigned)v < 1024u)) v = (int)__int_as_float(v);
        eidx[tid] = min(max(v, 0), NN-1);
    }
    if (tid < TE) ewS[tid] = ew[be0 + tid];
    if (tid < FF){ bmS[tid] = bm[tid]; gmS[tid] = gm[tid]; betamS[tid] = betam[tid]; }

    float acc[4][6];
    #pragma unroll
    for (int a=0;a<4;++a)
        #pragma unroll
        for (int c=0;c<6;++c) acc[a][c] = 0.f;

    const int e_st = tid >> 2;
    const int kk0  = (tid & 3) * 8;

    __syncthreads();

    for (int c = 0; c < 7; ++c){
        const int kbase = c * BK;
        __syncthreads();
        {
            const float4* src = (const float4*)(Wm + (size_t)kbase*FF);
            float4* dst = (float4*)&Ws[0][0];
            dst[tid      ] = src[tid      ];
            dst[tid + 256] = src[tid + 256];
            dst[tid + 512] = src[tid + 512];
        }
        {
            const float* rp;
            if (c < 3)      rp = nodes + (size_t)(b*NN + eidx[2*e_st  ])*FF + kbase;
            else if (c < 6) rp = nodes + (size_t)(b*NN + eidx[2*e_st+1])*FF + (kbase - FF);
            else            rp = ef + (size_t)(be0 + e_st)*FE;
            *(float4*)&Xs[e_st][kk0    ] = *(const float4*)(rp + kk0);
            *(float4*)&Xs[e_st][kk0 + 4] = *(const float4*)(rp + kk0 + 4);
        }
        __syncthreads();
        #pragma unroll 4
        for (int kk = 0; kk < BK; ++kk){
            float2 w01 = *(const float2*)&Ws[kk][6*tx    ];
            float2 w23 = *(const float2*)&Ws[kk][6*tx + 2];
            float2 w45 = *(const float2*)&Ws[kk][6*tx + 4];
            float xv[4];
            #pragma unroll
            for (int ei=0; ei<4; ++ei) xv[ei] = Xs[ty + 16*ei][kk];
            #pragma unroll
            for (int ei=0; ei<4; ++ei){
                acc[ei][0] += xv[ei]*w01.x;  acc[ei][1] += xv[ei]*w01.y;
                acc[ei][2] += xv[ei]*w23.x;  acc[ei][3] += xv[ei]*w23.y;
                acc[ei][4] += xv[ei]*w45.x;  acc[ei][5] += xv[ei]*w45.y;
            }
        }
    }

    #pragma unroll
    for (int ei = 0; ei < 4; ++ei){
        const int el = ty + 16*ei;
        float h[6]; float psum = 0.f;
        #pragma unroll
        for (int jj=0; jj<6; ++jj){
            h[jj] = gelu_erf(acc[ei][jj] + bmS[6*tx + jj]);
            psum += h[jj];
        }
        #pragma unroll
        for (int m=1; m<16; m<<=1) psum += __shfl_xor(psum, m, 16);
        const float mu = psum * (1.f/FF);
        float vsum = 0.f;
        #pragma unroll
        for (int jj=0; jj<6; ++jj){ float d = h[jj]-mu; vsum += d*d; }
        #pragma unroll
        for (int m=1; m<16; m<<=1) vsum += __shfl_xor(vsum, m, 16);
        const float rstd = rsqrtf(vsum*(1.f/FF) + 1e-3f);

        const float w = ewS[el];
        float* __restrict__ wrow = wm_out + (size_t)(be0 + el)*FF + 6*tx;
        #pragma unroll
        for (int jj=0; jj<6; ++jj)
            wrow[jj] = ((h[jj]-mu)*rstd*gmS[6*tx+jj] + betamS[6*tx+jj]) * w;
    }
}

// ---------------- Kernel 1b: CSR gather -> agg ----------------
__global__ __launch_bounds__(96) void gather_kernel(
    const float* __restrict__ wm_out, const float* __restrict__ ed,
    const int* __restrict__ elist, const int* __restrict__ rowstart,
    const int* __restrict__ cnt, float* __restrict__ agg)
{
    const int bn = blockIdx.x;       // b*N + n
    const int t  = threadIdx.x;      // 96
    const int beg = rowstart[bn];
    const int num = cnt[bn];
    float sum = 0.f;
    for (int i = 0; i < num; ++i){
        const int be = elist[beg + i];
        const float coeff = ed[2*(size_t)be + 1];
        sum += wm_out[(size_t)be*FF + t] * coeff;
    }
    agg[(size_t)bn*FF + t] = sum;
}

// ---------------- Kernel 2: QKVG projections (tiled GEMM) ----------------
__global__ __launch_bounds__(256) void qkvg_kernel(
    const float* __restrict__ nodes, const float* __restrict__ agg,
    const float* __restrict__ Wq, const float* __restrict__ bq,
    const float* __restrict__ Wk, const float* __restrict__ bk,
    const float* __restrict__ Wv, const float* __restrict__ bv,
    const float* __restrict__ Wg, const float* __restrict__ bg,
    float* __restrict__ qo, float* __restrict__ ko,
    float* __restrict__ vo, float* __restrict__ go)
{
    const int rt  = blockIdx.x;          // 128 row tiles
    const int m   = blockIdx.y;          // 0..3
    const int tid = threadIdx.x;
    const int tx  = tid & 15;
    const int ty  = tid >> 4;
    const int r0  = rt * TE;

    const float* W    = (m==0)?Wq:(m==1)?Wk:(m==2)?Wv:Wg;
    const float* bias = (m==0)?bq:(m==1)?bk:(m==2)?bv:bg;
    float* out        = (m==0)?qo:(m==1)?ko:(m==2)?vo:go;

    __shared__ float Xs[TE][BK+4];
    __shared__ float Ws[BK][FF];
    __shared__ float bS[FF];
    if (tid < FF) bS[tid] = bias[tid];

    float acc[4][6];
    #pragma unroll
    for (int a=0;a<4;++a)
        #pragma unroll
        for (int c=0;c<6;++c) acc[a][c] = 0.f;

    const int e_st = tid >> 2;
    const int kk0  = (tid & 3) * 8;

    for (int c = 0; c < 6; ++c){
        __syncthreads();
        {
            const float4* src = (const float4*)(W + (size_t)c*BK*FF);
            float4* dst = (float4*)&Ws[0][0];
            dst[tid      ] = src[tid      ];
            dst[tid + 256] = src[tid + 256];
            dst[tid + 512] = src[tid + 512];
        }
        {
            const float* rp = (c < 3)
                ? nodes + (size_t)(r0 + e_st)*FF + c*BK
                : agg   + (size_t)(r0 + e_st)*FF + (c-3)*BK;
            *(float4*)&Xs[e_st][kk0    ] = *(const float4*)(rp + kk0);
            *(float4*)&Xs[e_st][kk0 + 4] = *(const float4*)(rp + kk0 + 4);
        }
        __syncthreads();
        #pragma unroll 4
        for (int kk = 0; kk < BK; ++kk){
            float2 w01 = *(const float2*)&Ws[kk][6*tx    ];
            float2 w23 = *(const float2*)&Ws[kk][6*tx + 2];
            float2 w45 = *(const float2*)&Ws[kk][6*tx + 4];
            float xv[4];
            #pragma unroll
            for (int ei=0; ei<4; ++ei) xv[ei] = Xs[ty + 16*ei][kk];
            #pragma unroll
            for (int ei=0; ei<4; ++ei){
                acc[ei][0] += xv[ei]*w01.x;  acc[ei][1] += xv[ei]*w01.y;
                acc[ei][2] += xv[ei]*w23.x;  acc[ei][3] += xv[ei]*w23.y;
                acc[ei][4] += xv[ei]*w45.x;  acc[ei][5] += xv[ei]*w45.y;
            }
        }
    }

    #pragma unroll
    for (int ei = 0; ei < 4; ++ei){
        const int row = r0 + ty + 16*ei;
        float* __restrict__ orow = out + (size_t)row*FF + 6*tx;
        #pragma unroll
        for (int jj=0; jj<6; ++jj) orow[jj] = acc[ei][jj] + bS[6*tx + jj];
    }
}

// ---------------- Kernel 3: gated attention (K-split flash, reg prefetch) --
// block = 256 thr = 4 waves per (b, h, 64-row q-tile). Wave w handles keys
// [256w, 256w+256) for all 64 q-rows (one row per lane); partials merged in
// LDS. Key loop software-pipelines: K/V for key j+1 are issued before the
// compute of key j, breaking the per-iteration load->use latency chain.
// NOTE: the final prefetch reads row kc0+256 (one 96-float row past the
// 1024-key slice for w=3). This lands in the adjacent workspace buffer
// (ko->vo->go, all allocated) and its values are never consumed.
// att MAY alias g: merge-phase reads g then writes att at the same address
// from the same thread.
__global__ __launch_bounds__(256) void attn_kernel(
    const float* __restrict__ q, const float* __restrict__ k,
    const float* __restrict__ v, const float* g,
    float* att)
{
    const int blk = blockIdx.x;
    const int qt = blk & 15;              // N/64 = 16 tiles
    const int h  = (blk >> 4) % NH;
    const int b  = blk / (16*NH);
    const int tid  = threadIdx.x;
    const int lane = tid & 63;
    const int w    = tid >> 6;            // 0..3 (k-split)
    const int qrow = qt*64 + lane;
    const size_t base = (size_t)(b*NN)*FF + h*DD;

    float qr[DD];
    const float* qp = q + base + (size_t)qrow*FF;
    #pragma unroll
    for (int i=0;i<DD;++i) qr[i] = qp[i] * 0.35355339059327373f;   // 1/sqrt(8)

    float m = -1e30f, l = 0.f, o[DD];
    #pragma unroll
    for (int i=0;i<DD;++i) o[i] = 0.f;

    const int kc0 = w * 256;
    const float* kp = k + base + (size_t)kc0*FF;
    const float* vp = v + base + (size_t)kc0*FF;

    // prime the pipeline: key 0
    float4 k0 = *(const float4*)(kp);
    float4 k1 = *(const float4*)(kp + 4);
    float4 v0 = *(const float4*)(vp);
    float4 v1 = *(const float4*)(vp + 4);

    #pragma unroll 4
    for (int j = 0; j < 256; ++j){
        // rotate current key into working regs
        const float4 ck0 = k0, ck1 = k1, cv0 = v0, cv1 = v1;
        // issue prefetch for key j+1 (one-row overread at the very end; safe)
        kp += FF; vp += FF;
        k0 = *(const float4*)(kp);
        k1 = *(const float4*)(kp + 4);
        v0 = *(const float4*)(vp);
        v1 = *(const float4*)(vp + 4);

        float s = qr[0]*ck0.x + qr[1]*ck0.y + qr[2]*ck0.z + qr[3]*ck0.w
                + qr[4]*ck1.x + qr[5]*ck1.y + qr[6]*ck1.z + qr[7]*ck1.w;
        float mn = fmaxf(m, s);
        float c = __expf(m - mn);
        float p = __expf(s - mn);
        l = l*c + p;
        o[0] = o[0]*c + p*cv0.x;  o[1] = o[1]*c + p*cv0.y;
        o[2] = o[2]*c + p*cv0.z;  o[3] = o[3]*c + p*cv0.w;
        o[4] = o[4]*c + p*cv1.x;  o[5] = o[5]*c + p*cv1.y;
        o[6] = o[6]*c + p*cv1.z;  o[7] = o[7]*c + p*cv1.w;
        m = mn;
    }

    __shared__ float mS[4][64], lS[4][64], oS[4][64][DD+1];
    mS[w][lane] = m;
    lS[w][lane] = l;
    #pragma unroll
    for (int i=0;i<DD;++i) oS[w][lane][i] = o[i];
    __syncthreads();

    if (tid < 64){
        float M = mS[0][lane];
        #pragma unroll
        for (int w2=1; w2<4; ++w2) M = fmaxf(M, mS[w2][lane]);
        float L = 0.f, O[DD];
        #pragma unroll
        for (int i=0;i<DD;++i) O[i] = 0.f;
        #pragma unroll
        for (int w2=0; w2<4; ++w2){
            const float c = __expf(mS[w2][lane] - M);
            L += lS[w2][lane] * c;
            #pragma unroll
            for (int i=0;i<DD;++i) O[i] += oS[w2][lane][i] * c;
        }
        const float inv = 1.f / L;
        const float* gp = g + base + (size_t)qrow*FF;
        float* ap = att + base + (size_t)qrow*FF;
        #pragma unroll
        for (int i=0;i<DD;++i){
            const float gate = 1.f/(1.f + __expf(-gp[i]));
            ap[i] = O[i]*inv*gate;
        }
    }
}

// ---------------- Kernel 4: output projection (tiled GEMM + GELU + LN) ----
__global__ __launch_bounds__(256) void out_kernel(
    const float* __restrict__ att, const float* __restrict__ Wo, const float* __restrict__ bo,
    const float* __restrict__ gu, const float* __restrict__ betau,
    float* __restrict__ out0)
{
    const int rt  = blockIdx.x;
    const int tid = threadIdx.x;
    const int tx  = tid & 15;
    const int ty  = tid >> 4;
    const int r0  = rt * TE;

    __shared__ float Xs[TE][BK+4];
    __shared__ float Ws[BK][FF];
    __shared__ float boS[FF], guS[FF], beS[FF];
    if (tid < FF){ boS[tid] = bo[tid]; guS[tid] = gu[tid]; beS[tid] = betau[tid]; }

    float acc[4][6];
    #pragma unroll
    for (int a=0;a<4;++a)
        #pragma unroll
        for (int c=0;c<6;++c) acc[a][c] = 0.f;

    const int e_st = tid >> 2;
    const int kk0  = (tid & 3) * 8;

    for (int c = 0; c < 3; ++c){
        __syncthreads();
        {
            const float4* src = (const float4*)(Wo + (size_t)c*BK*FF);
            float4* dst = (float4*)&Ws[0][0];
            dst[tid      ] = src[tid      ];
            dst[tid + 256] = src[tid + 256];
            dst[tid + 512] = src[tid + 512];
        }
        {
            const float* rp = att + (size_t)(r0 + e_st)*FF + c*BK;
            *(float4*)&Xs[e_st][kk0    ] = *(const float4*)(rp + kk0);
            *(float4*)&Xs[e_st][kk0 + 4] = *(const float4*)(rp + kk0 + 4);
        }
        __syncthreads();
        #pragma unroll 4
        for (int kk = 0; kk < BK; ++kk){
            float2 w01 = *(const float2*)&Ws[kk][6*tx    ];
            float2 w23 = *(const float2*)&Ws[kk][6*tx + 2];
            float2 w45 = *(const float2*)&Ws[kk][6*tx + 4];
            float xv[4];
            #pragma unroll
            for (int ei=0; ei<4; ++ei) xv[ei] = Xs[ty + 16*ei][kk];
            #pragma unroll
            for (int ei=0; ei<4; ++ei){
                acc[ei][0] += xv[ei]*w01.x;  acc[ei][1] += xv[ei]*w01.y;
                acc[ei][2] += xv[ei]*w23.x;  acc[ei][3] += xv[ei]*w23.y;
                acc[ei][4] += xv[ei]*w45.x;  acc[ei][5] += xv[ei]*w45.y;
            }
        }
    }

    #pragma unroll
    for (int ei = 0; ei < 4; ++ei){
        const int row = r0 + ty + 16*ei;
        float h[6]; float psum = 0.f;
        #pragma unroll
        for (int jj=0; jj<6; ++jj){
            h[jj] = gelu_erf(acc[ei][jj] + boS[6*tx + jj]);
            psum += h[jj];
        }
        #pragma unroll
        for (int m=1; m<16; m<<=1) psum += __shfl_xor(psum, m, 16);
        const float mu = psum * (1.f/FF);
        float vsum = 0.f;
        #pragma unroll
        for (int jj=0; jj<6; ++jj){ float d = h[jj]-mu; vsum += d*d; }
        #pragma unroll
        for (int m=1; m<16; m<<=1) vsum += __shfl_xor(vsum, m, 16);
        const float rstd = rsqrtf(vsum*(1.f/FF) + 1e-3f);
        float* __restrict__ orow = out0 + (size_t)row*FF + 6*tx;
        #pragma unroll
        for (int jj=0; jj<6; ++jj)
            orow[jj] = (h[jj]-mu)*rstd*guS[6*tx+jj] + beS[6*tx+jj];
    }
}

// ---------------- Kernel 5: pass-through outputs (fp32) ----------------
__global__ void passthrough_kernel(const int* __restrict__ edges,
    const float* __restrict__ ew, const float* __restrict__ ed,
    float* __restrict__ o_edges, float* __restrict__ o_ew, float* __restrict__ o_ed)
{
    const int i = blockIdx.x*blockDim.x + threadIdx.x;
    const int NE2 = BB*EE*2;
    const int NW  = BB*EE;
    if (i < NE2)                 o_edges[i] = (float)load_idx(edges, i);
    else if (i < NE2+NW)         o_ew[i-NE2] = ew[i-NE2];
    else if (i < NE2+NW+NE2)     o_ed[i-NE2-NW] = ed[i-NE2-NW];
}

extern "C" void kernel_launch(void* const* d_in, const int* in_sizes, int n_in,
                              void* d_out, int out_size, void* d_ws, size_t ws_size,
                              hipStream_t stream) {
    // ---- adaptive input mapping by element count (dict-order tiebreak) ----
    int i_nodes=-1, i_ef=-1, i_edges=-1, i_ed=-1, i_ew=-1, i_Wm=-1, i_Wo=-1;
    int i_W4[4]; int nW4=0;
    int i_v96[10]; int nv96=0;
    for (int i = 0; i < n_in; ++i){
        const int s = in_sizes[i];
        if      (s == 786432)  i_nodes = i;
        else if (s == 4194304) i_ef = i;
        else if (s == 262144)  { if (i_edges < 0) i_edges = i; else i_ed = i; }
        else if (s == 131072)  i_ew = i;
        else if (s == 21504)   i_Wm = i;
        else if (s == 18432)   { if (nW4 < 4) i_W4[nW4++] = i; }
        else if (s == 9216)    i_Wo = i;
        else if (s == 96)      { if (nv96 < 10) i_v96[nv96++] = i; }
    }
    const float* nodes = (const float*)d_in[i_nodes];
    const float* ef    = (const float*)d_in[i_ef];
    const int*   edges = (const int*)d_in[i_edges];
    const float* ew    = (const float*)d_in[i_ew];
    const float* ed    = (const float*)d_in[i_ed];
    const float* Wm = (const float*)d_in[i_Wm];
    const float* Wq = (const float*)d_in[i_W4[0]];
    const float* Wk = (const float*)d_in[i_W4[1]];
    const float* Wv = (const float*)d_in[i_W4[2]];
    const float* Wg = (const float*)d_in[i_W4[3]];
    const float* Wo = (const float*)d_in[i_Wo];
    const float* bm    = (const float*)d_in[i_v96[0]];
    const float* gm    = (const float*)d_in[i_v96[1]];
    const float* betam = (const float*)d_in[i_v96[2]];
    const float* bq    = (const float*)d_in[i_v96[3]];
    const float* bk    = (const float*)d_in[i_v96[4]];
    const float* bv    = (const float*)d_in[i_v96[5]];
    const float* bg    = (const float*)d_in[i_v96[6]];
    const float* bo    = (const float*)d_in[i_v96[7]];
    const float* gu    = (const float*)d_in[i_v96[8]];
    const float* betau = (const float*)d_in[i_v96[9]];

    // ---- output layout: fp32, reference return order ----
    float* outp = (float*)d_out;
    const size_t ROWS  = (size_t)BB*NN*FF;     // 786432
    const size_t WMSZ  = (size_t)BB*EE*FF;     // 12582912
    const size_t NE2   = (size_t)BB*EE*2;      // 262144
    const size_t NW    = (size_t)BB*EE;        // 131072
    float* out_un    = outp;
    float* out_wm    = outp + ROWS;
    float* out_edges = outp + ROWS + WMSZ;
    float* out_ew    = outp + ROWS + WMSZ + NE2;
    float* out_ed    = outp + ROWS + WMSZ + NE2 + NW;

    // ---- workspace layout ----
    float* ws  = (float*)d_ws;
    float* agg = ws;
    float* qo  = ws + 1*ROWS;
    float* ko  = ws + 2*ROWS;
    float* vo  = ws + 3*ROWS;
    float* go  = ws + 4*ROWS;       // att aliases go (safe: same-thread RMW)
    float* att = go;
    int* ints      = (int*)(ws + 5*ROWS);
    int* cnt       = ints;                    // B*N
    int* rowstart  = ints + BB*NN;            // B*N
    int* cursor    = ints + 2*BB*NN;          // B*N
    int* elist     = ints + 3*BB*NN;          // B*E

    hipMemsetAsync(cnt, 0, BB*NN*sizeof(int), stream);

    // CSR build (independent of GEMM)
    hist_kernel<<<(BB*EE+255)/256, 256, 0, stream>>>(edges, cnt);
    scan_kernel<<<BB, NN, 0, stream>>>(cnt, rowstart, cursor);
    scatter_kernel<<<(BB*EE+255)/256, 256, 0, stream>>>(edges, cursor, elist);

    // edge messages (writes wm only; no atomics)
    edge_msg_kernel<<<(BB*EE)/TE, 256, 0, stream>>>(nodes, ef, edges, ew,
                                               Wm, bm, gm, betam, out_wm);
    // CSR gather -> agg
    gather_kernel<<<BB*NN, 96, 0, stream>>>(out_wm, ed, elist, rowstart, cnt, agg);

    dim3 qgrid((BB*NN)/TE, 4);
    qkvg_kernel<<<qgrid, 256, 0, stream>>>(nodes, agg, Wq, bq, Wk, bk, Wv, bv,
                                           Wg, bg, qo, ko, vo, go);
    attn_kernel<<<BB*NH*16, 256, 0, stream>>>(qo, ko, vo, go, att);
    out_kernel<<<(BB*NN)/TE, 256, 0, stream>>>(att, Wo, bo, gu, betau, out_un);

    const int npass = (int)(NE2 + NW + NE2);
    passthrough_kernel<<<(npass+255)/256, 256, 0, stream>>>(edges, ew, ed,
                                               out_edges, out_ew, out_ed);
}

// Round 10
// 398.222 us; speedup vs baseline: 1.1428x; 1.1423x over previous
//
#include <hip/hip_runtime.h>
#include <hip/hip_bf16.h>

#define BB 8
#define NN 1024
#define EE 16384
#define FF 96
#define FE 32
#define NH 12
#define DD 8
#define KM 224   // 2F + Fe
#define KX 192   // 2F
#define TE 64    // rows per GEMM tile
#define BK 32    // K chunk

__device__ __forceinline__ float gelu_erf(float x){
    return 0.5f * x * (1.0f + erff(x * 0.70710678118654752f));
}

__device__ __forceinline__ int load_idx(const int* __restrict__ p, int i){
    int v = p[i];
    if (!((unsigned)v < 1024u)) v = (int)__int_as_float(v);
    return min(max(v, 0), NN-1);
}

// ---------------- CSR build: histogram ----------------
__global__ __launch_bounds__(256) void hist_kernel(
    const int* __restrict__ edges, int* __restrict__ cnt)
{
    const int i = blockIdx.x*blockDim.x + threadIdx.x;   // b*E + e
    if (i < BB*EE){
        const int b = i >> 14;
        const int dst = load_idx(edges, 2*i+1);
        atomicAdd(&cnt[b*NN + dst], 1);
    }
}

// ---------------- CSR build: per-batch exclusive scan (N=1024) ----------------
__global__ __launch_bounds__(1024) void scan_kernel(
    const int* __restrict__ cnt, int* __restrict__ rowstart, int* __restrict__ cursor)
{
    const int b = blockIdx.x;
    const int t = threadIdx.x;
    __shared__ int s[NN];
    const int v = cnt[b*NN + t];
    s[t] = v;
    __syncthreads();
    for (int off = 1; off < NN; off <<= 1){
        int u = (t >= off) ? s[t-off] : 0;
        __syncthreads();
        s[t] += u;
        __syncthreads();
    }
    const int ex = s[t] - v + b*EE;     // exclusive, offset by batch base
    rowstart[b*NN + t] = ex;
    cursor[b*NN + t]   = ex;
}

// ---------------- CSR build: scatter edge ids ----------------
__global__ __launch_bounds__(256) void scatter_kernel(
    const int* __restrict__ edges, int* __restrict__ cursor, int* __restrict__ elist)
{
    const int i = blockIdx.x*blockDim.x + threadIdx.x;   // global edge id
    if (i < BB*EE){
        const int b = i >> 14;
        const int dst = load_idx(edges, 2*i+1);
        const int pos = atomicAdd(&cursor[b*NN + dst], 1);
        elist[pos] = i;
    }
}

// ---------------- Kernel 1: edge messages (tiled GEMM + fused epilogue) ----
__global__ __launch_bounds__(256) void edge_msg_kernel(
    const float* __restrict__ nodes, const float* __restrict__ ef,
    const int*  __restrict__ edges, const float* __restrict__ ew,
    const float* __restrict__ Wm, const float* __restrict__ bm,
    const float* __restrict__ gm, const float* __restrict__ betam,
    float* __restrict__ wm_out)
{
    const int bid = blockIdx.x;
    const int tid = threadIdx.x;
    const int tx  = tid & 15;
    const int ty  = tid >> 4;
    const int be0 = bid * TE;
    const int b   = be0 >> 14;

    __shared__ float Xs[TE][BK+4];
    __shared__ float Ws[BK][FF];
    __shared__ int   eidx[TE*2];
    __shared__ float ewS[TE];
    __shared__ float bmS[FF], gmS[FF], betamS[FF];

    if (tid < TE*2){
        int v = edges[(size_t)be0*2 + tid];
        if (!((unsigned)v < 1024u)) v = (int)__int_as_float(v);
        eidx[tid] = min(max(v, 0), NN-1);
    }
    if (tid < TE) ewS[tid] = ew[be0 + tid];
    if (tid < FF){ bmS[tid] = bm[tid]; gmS[tid] = gm[tid]; betamS[tid] = betam[tid]; }

    float acc[4][6];
    #pragma unroll
    for (int a=0;a<4;++a)
        #pragma unroll
        for (int c=0;c<6;++c) acc[a][c] = 0.f;

    const int e_st = tid >> 2;
    const int kk0  = (tid & 3) * 8;

    __syncthreads();

    for (int c = 0; c < 7; ++c){
        const int kbase = c * BK;
        __syncthreads();
        {
            const float4* src = (const float4*)(Wm + (size_t)kbase*FF);
            float4* dst = (float4*)&Ws[0][0];
            dst[tid      ] = src[tid      ];
            dst[tid + 256] = src[tid + 256];
            dst[tid + 512] = src[tid + 512];
        }
        {
            const float* rp;
            if (c < 3)      rp = nodes + (size_t)(b*NN + eidx[2*e_st  ])*FF + kbase;
            else if (c < 6) rp = nodes + (size_t)(b*NN + eidx[2*e_st+1])*FF + (kbase - FF);
            else            rp = ef + (size_t)(be0 + e_st)*FE;
            *(float4*)&Xs[e_st][kk0    ] = *(const float4*)(rp + kk0);
            *(float4*)&Xs[e_st][kk0 + 4] = *(const float4*)(rp + kk0 + 4);
        }
        __syncthreads();
        #pragma unroll 4
        for (int kk = 0; kk < BK; ++kk){
            float2 w01 = *(const float2*)&Ws[kk][6*tx    ];
            float2 w23 = *(const float2*)&Ws[kk][6*tx + 2];
            float2 w45 = *(const float2*)&Ws[kk][6*tx + 4];
            float xv[4];
            #pragma unroll
            for (int ei=0; ei<4; ++ei) xv[ei] = Xs[ty + 16*ei][kk];
            #pragma unroll
            for (int ei=0; ei<4; ++ei){
                acc[ei][0] += xv[ei]*w01.x;  acc[ei][1] += xv[ei]*w01.y;
                acc[ei][2] += xv[ei]*w23.x;  acc[ei][3] += xv[ei]*w23.y;
                acc[ei][4] += xv[ei]*w45.x;  acc[ei][5] += xv[ei]*w45.y;
            }
        }
    }

    #pragma unroll
    for (int ei = 0; ei < 4; ++ei){
        const int el = ty + 16*ei;
        float h[6]; float psum = 0.f;
        #pragma unroll
        for (int jj=0; jj<6; ++jj){
            h[jj] = gelu_erf(acc[ei][jj] + bmS[6*tx + jj]);
            psum += h[jj];
        }
        #pragma unroll
        for (int m=1; m<16; m<<=1) psum += __shfl_xor(psum, m, 16);
        const float mu = psum * (1.f/FF);
        float vsum = 0.f;
        #pragma unroll
        for (int jj=0; jj<6; ++jj){ float d = h[jj]-mu; vsum += d*d; }
        #pragma unroll
        for (int m=1; m<16; m<<=1) vsum += __shfl_xor(vsum, m, 16);
        const float rstd = rsqrtf(vsum*(1.f/FF) + 1e-3f);

        const float w = ewS[el];
        float* __restrict__ wrow = wm_out + (size_t)(be0 + el)*FF + 6*tx;
        #pragma unroll
        for (int jj=0; jj<6; ++jj)
            wrow[jj] = ((h[jj]-mu)*rstd*gmS[6*tx+jj] + betamS[6*tx+jj]) * w;
    }
}

// ---------------- Kernel 1b: CSR gather -> agg ----------------
__global__ __launch_bounds__(96) void gather_kernel(
    const float* __restrict__ wm_out, const float* __restrict__ ed,
    const int* __restrict__ elist, const int* __restrict__ rowstart,
    const int* __restrict__ cnt, float* __restrict__ agg)
{
    const int bn = blockIdx.x;       // b*N + n
    const int t  = threadIdx.x;      // 96
    const int beg = rowstart[bn];
    const int num = cnt[bn];
    float sum = 0.f;
    for (int i = 0; i < num; ++i){
        const int be = elist[beg + i];
        const float coeff = ed[2*(size_t)be + 1];
        sum += wm_out[(size_t)be*FF + t] * coeff;
    }
    agg[(size_t)bn*FF + t] = sum;
}

// ---------------- Kernel 2: QKVG projections (tiled GEMM) ----------------
__global__ __launch_bounds__(256) void qkvg_kernel(
    const float* __restrict__ nodes, const float* __restrict__ agg,
    const float* __restrict__ Wq, const float* __restrict__ bq,
    const float* __restrict__ Wk, const float* __restrict__ bk,
    const float* __restrict__ Wv, const float* __restrict__ bv,
    const float* __restrict__ Wg, const float* __restrict__ bg,
    float* __restrict__ qo, float* __restrict__ ko,
    float* __restrict__ vo, float* __restrict__ go)
{
    const int rt  = blockIdx.x;          // 128 row tiles
    const int m   = blockIdx.y;          // 0..3
    const int tid = threadIdx.x;
    const int tx  = tid & 15;
    const int ty  = tid >> 4;
    const int r0  = rt * TE;

    const float* W    = (m==0)?Wq:(m==1)?Wk:(m==2)?Wv:Wg;
    const float* bias = (m==0)?bq:(m==1)?bk:(m==2)?bv:bg;
    float* out        = (m==0)?qo:(m==1)?ko:(m==2)?vo:go;

    __shared__ float Xs[TE][BK+4];
    __shared__ float Ws[BK][FF];
    __shared__ float bS[FF];
    if (tid < FF) bS[tid] = bias[tid];

    float acc[4][6];
    #pragma unroll
    for (int a=0;a<4;++a)
        #pragma unroll
        for (int c=0;c<6;++c) acc[a][c] = 0.f;

    const int e_st = tid >> 2;
    const int kk0  = (tid & 3) * 8;

    for (int c = 0; c < 6; ++c){
        __syncthreads();
        {
            const float4* src = (const float4*)(W + (size_t)c*BK*FF);
            float4* dst = (float4*)&Ws[0][0];
            dst[tid      ] = src[tid      ];
            dst[tid + 256] = src[tid + 256];
            dst[tid + 512] = src[tid + 512];
        }
        {
            const float* rp = (c < 3)
                ? nodes + (size_t)(r0 + e_st)*FF + c*BK
                : agg   + (size_t)(r0 + e_st)*FF + (c-3)*BK;
            *(float4*)&Xs[e_st][kk0    ] = *(const float4*)(rp + kk0);
            *(float4*)&Xs[e_st][kk0 + 4] = *(const float4*)(rp + kk0 + 4);
        }
        __syncthreads();
        #pragma unroll 4
        for (int kk = 0; kk < BK; ++kk){
            float2 w01 = *(const float2*)&Ws[kk][6*tx    ];
            float2 w23 = *(const float2*)&Ws[kk][6*tx + 2];
            float2 w45 = *(const float2*)&Ws[kk][6*tx + 4];
            float xv[4];
            #pragma unroll
            for (int ei=0; ei<4; ++ei) xv[ei] = Xs[ty + 16*ei][kk];
            #pragma unroll
            for (int ei=0; ei<4; ++ei){
                acc[ei][0] += xv[ei]*w01.x;  acc[ei][1] += xv[ei]*w01.y;
                acc[ei][2] += xv[ei]*w23.x;  acc[ei][3] += xv[ei]*w23.y;
                acc[ei][4] += xv[ei]*w45.x;  acc[ei][5] += xv[ei]*w45.y;
            }
        }
    }

    #pragma unroll
    for (int ei = 0; ei < 4; ++ei){
        const int row = r0 + ty + 16*ei;
        float* __restrict__ orow = out + (size_t)row*FF + 6*tx;
        #pragma unroll
        for (int jj=0; jj<6; ++jj) orow[jj] = acc[ei][jj] + bS[6*tx + jj];
    }
}

// ---------------- Kernel 3: gated attention (LDS-staged flash) ----------
// block = 256 thr = 4 waves per (b, h, 64-row q-tile).
// lane decomposition: r = lane&15 (row within wave), s = lane>>4 (key stream).
// wave w owns q-rows [16w, 16w+16). Keys staged in 128-key LDS chunks by the
// whole block (coalesced); each lane walks keys {4*jj + s} from LDS — the 4
// distinct addresses per wave are 12 banks apart (48 B rows) = conflict-free,
// and the 16 same-address lanes broadcast. Per-row k-split partials merged
// in-register via __shfl_xor(16/32) at the end.
// att MAY alias g: the final phase reads g then writes att at the same
// address from the same thread.
__global__ __launch_bounds__(256) void attn_kernel(
    const float* __restrict__ q, const float* __restrict__ k,
    const float* __restrict__ v, const float* g,
    float* att)
{
    const int blk = blockIdx.x;
    const int qt = blk & 15;              // N/64 = 16 tiles
    const int h  = (blk >> 4) % NH;
    const int b  = blk / (16*NH);
    const int tid  = threadIdx.x;
    const int lane = tid & 63;
    const int w    = tid >> 6;            // wave id 0..3
    const int r    = lane & 15;           // row within wave
    const int s    = lane >> 4;           // key stream 0..3
    const int qrow = qt*64 + w*16 + r;
    const size_t base = (size_t)(b*NN)*FF + h*DD;

    __shared__ float Ks[128][12];         // 48 B rows: b128-aligned, 12 banks apart
    __shared__ float Vs[128][12];

    float qr[DD];
    const float* qp = q + base + (size_t)qrow*FF;
    #pragma unroll
    for (int i=0;i<DD;++i) qr[i] = qp[i] * 0.35355339059327373f;   // 1/sqrt(8)

    float m = -1e30f, l = 0.f, o[DD];
    #pragma unroll
    for (int i=0;i<DD;++i) o[i] = 0.f;

    const int skey  = tid >> 1;           // staging: 2 threads per key
    const int shalf = (tid & 1) * 4;      // floats 0-3 / 4-7

    for (int kc = 0; kc < NN; kc += 128){
        __syncthreads();                  // protect previous chunk
        {
            const float* kp = k + base + (size_t)(kc + skey)*FF + shalf;
            const float* vp = v + base + (size_t)(kc + skey)*FF + shalf;
            *(float4*)&Ks[skey][shalf] = *(const float4*)kp;
            *(float4*)&Vs[skey][shalf] = *(const float4*)vp;
        }
        __syncthreads();
        #pragma unroll 4
        for (int jj = 0; jj < 32; ++jj){
            const int key = 4*jj + s;
            float4 k0 = *(const float4*)&Ks[key][0];
            float4 k1 = *(const float4*)&Ks[key][4];
            float4 v0 = *(const float4*)&Vs[key][0];
            float4 v1 = *(const float4*)&Vs[key][4];
            float sc = qr[0]*k0.x + qr[1]*k0.y + qr[2]*k0.z + qr[3]*k0.w
                     + qr[4]*k1.x + qr[5]*k1.y + qr[6]*k1.z + qr[7]*k1.w;
            float mn = fmaxf(m, sc);
            float c = __expf(m - mn);
            float p = __expf(sc - mn);
            l = l*c + p;
            o[0] = o[0]*c + p*v0.x;  o[1] = o[1]*c + p*v0.y;
            o[2] = o[2]*c + p*v0.z;  o[3] = o[3]*c + p*v0.w;
            o[4] = o[4]*c + p*v1.x;  o[5] = o[5]*c + p*v1.y;
            o[6] = o[6]*c + p*v1.z;  o[7] = o[7]*c + p*v1.w;
            m = mn;
        }
    }

    // merge the 4 key-stream partials per row, in-register (lanes r, r+16, r+32, r+48)
    #pragma unroll
    for (int mask = 16; mask <= 32; mask <<= 1){
        const float m2 = __shfl_xor(m, mask);
        const float l2 = __shfl_xor(l, mask);
        float o2[DD];
        #pragma unroll
        for (int i=0;i<DD;++i) o2[i] = __shfl_xor(o[i], mask);
        const float M  = fmaxf(m, m2);
        const float c1 = __expf(m - M);
        const float c2 = __expf(m2 - M);
        l = l*c1 + l2*c2;
        #pragma unroll
        for (int i=0;i<DD;++i) o[i] = o[i]*c1 + o2[i]*c2;
        m = M;
    }

    if (s == 0){
        const float inv = 1.f / l;
        const float* gp = g + base + (size_t)qrow*FF;
        float* ap = att + base + (size_t)qrow*FF;
        #pragma unroll
        for (int i=0;i<DD;++i){
            const float gate = 1.f/(1.f + __expf(-gp[i]));
            ap[i] = o[i]*inv*gate;
        }
    }
}

// ---------------- Kernel 4: output projection (tiled GEMM + GELU + LN) ----
__global__ __launch_bounds__(256) void out_kernel(
    const float* __restrict__ att, const float* __restrict__ Wo, const float* __restrict__ bo,
    const float* __restrict__ gu, const float* __restrict__ betau,
    float* __restrict__ out0)
{
    const int rt  = blockIdx.x;
    const int tid = threadIdx.x;
    const int tx  = tid & 15;
    const int ty  = tid >> 4;
    const int r0  = rt * TE;

    __shared__ float Xs[TE][BK+4];
    __shared__ float Ws[BK][FF];
    __shared__ float boS[FF], guS[FF], beS[FF];
    if (tid < FF){ boS[tid] = bo[tid]; guS[tid] = gu[tid]; beS[tid] = betau[tid]; }

    float acc[4][6];
    #pragma unroll
    for (int a=0;a<4;++a)
        #pragma unroll
        for (int c=0;c<6;++c) acc[a][c] = 0.f;

    const int e_st = tid >> 2;
    const int kk0  = (tid & 3) * 8;

    for (int c = 0; c < 3; ++c){
        __syncthreads();
        {
            const float4* src = (const float4*)(Wo + (size_t)c*BK*FF);
            float4* dst = (float4*)&Ws[0][0];
            dst[tid      ] = src[tid      ];
            dst[tid + 256] = src[tid + 256];
            dst[tid + 512] = src[tid + 512];
        }
        {
            const float* rp = att + (size_t)(r0 + e_st)*FF + c*BK;
            *(float4*)&Xs[e_st][kk0    ] = *(const float4*)(rp + kk0);
            *(float4*)&Xs[e_st][kk0 + 4] = *(const float4*)(rp + kk0 + 4);
        }
        __syncthreads();
        #pragma unroll 4
        for (int kk = 0; kk < BK; ++kk){
            float2 w01 = *(const float2*)&Ws[kk][6*tx    ];
            float2 w23 = *(const float2*)&Ws[kk][6*tx + 2];
            float2 w45 = *(const float2*)&Ws[kk][6*tx + 4];
            float xv[4];
            #pragma unroll
            for (int ei=0; ei<4; ++ei) xv[ei] = Xs[ty + 16*ei][kk];
            #pragma unroll
            for (int ei=0; ei<4; ++ei){
                acc[ei][0] += xv[ei]*w01.x;  acc[ei][1] += xv[ei]*w01.y;
                acc[ei][2] += xv[ei]*w23.x;  acc[ei][3] += xv[ei]*w23.y;
                acc[ei][4] += xv[ei]*w45.x;  acc[ei][5] += xv[ei]*w45.y;
            }
        }
    }

    #pragma unroll
    for (int ei = 0; ei < 4; ++ei){
        const int row = r0 + ty + 16*ei;
        float h[6]; float psum = 0.f;
        #pragma unroll
        for (int jj=0; jj<6; ++jj){
            h[jj] = gelu_erf(acc[ei][jj] + boS[6*tx + jj]);
            psum += h[jj];
        }
        #pragma unroll
        for (int m=1; m<16; m<<=1) psum += __shfl_xor(psum, m, 16);
        const float mu = psum * (1.f/FF);
        float vsum = 0.f;
        #pragma unroll
        for (int jj=0; jj<6; ++jj){ float d = h[jj]-mu; vsum += d*d; }
        #pragma unroll
        for (int m=1; m<16; m<<=1) vsum += __shfl_xor(vsum, m, 16);
        const float rstd = rsqrtf(vsum*(1.f/FF) + 1e-3f);
        float* __restrict__ orow = out0 + (size_t)row*FF + 6*tx;
        #pragma unroll
        for (int jj=0; jj<6; ++jj)
            orow[jj] = (h[jj]-mu)*rstd*guS[6*tx+jj] + beS[6*tx+jj];
    }
}

// ---------------- Kernel 5: pass-through outputs (fp32) ----------------
__global__ void passthrough_kernel(const int* __restrict__ edges,
    const float* __restrict__ ew, const float* __restrict__ ed,
    float* __restrict__ o_edges, float* __restrict__ o_ew, float* __restrict__ o_ed)
{
    const int i = blockIdx.x*blockDim.x + threadIdx.x;
    const int NE2 = BB*EE*2;
    const int NW  = BB*EE;
    if (i < NE2)                 o_edges[i] = (float)load_idx(edges, i);
    else if (i < NE2+NW)         o_ew[i-NE2] = ew[i-NE2];
    else if (i < NE2+NW+NE2)     o_ed[i-NE2-NW] = ed[i-NE2-NW];
}

extern "C" void kernel_launch(void* const* d_in, const int* in_sizes, int n_in,
                              void* d_out, int out_size, void* d_ws, size_t ws_size,
                              hipStream_t stream) {
    // ---- adaptive input mapping by element count (dict-order tiebreak) ----
    int i_nodes=-1, i_ef=-1, i_edges=-1, i_ed=-1, i_ew=-1, i_Wm=-1, i_Wo=-1;
    int i_W4[4]; int nW4=0;
    int i_v96[10]; int nv96=0;
    for (int i = 0; i < n_in; ++i){
        const int s = in_sizes[i];
        if      (s == 786432)  i_nodes = i;
        else if (s == 4194304) i_ef = i;
        else if (s == 262144)  { if (i_edges < 0) i_edges = i; else i_ed = i; }
        else if (s == 131072)  i_ew = i;
        else if (s == 21504)   i_Wm = i;
        else if (s == 18432)   { if (nW4 < 4) i_W4[nW4++] = i; }
        else if (s == 9216)    i_Wo = i;
        else if (s == 96)      { if (nv96 < 10) i_v96[nv96++] = i; }
    }
    const float* nodes = (const float*)d_in[i_nodes];
    const float* ef    = (const float*)d_in[i_ef];
    const int*   edges = (const int*)d_in[i_edges];
    const float* ew    = (const float*)d_in[i_ew];
    const float* ed    = (const float*)d_in[i_ed];
    const float* Wm = (const float*)d_in[i_Wm];
    const float* Wq = (const float*)d_in[i_W4[0]];
    const float* Wk = (const float*)d_in[i_W4[1]];
    const float* Wv = (const float*)d_in[i_W4[2]];
    const float* Wg = (const float*)d_in[i_W4[3]];
    const float* Wo = (const float*)d_in[i_Wo];
    const float* bm    = (const float*)d_in[i_v96[0]];
    const float* gm    = (const float*)d_in[i_v96[1]];
    const float* betam = (const float*)d_in[i_v96[2]];
    const float* bq    = (const float*)d_in[i_v96[3]];
    const float* bk    = (const float*)d_in[i_v96[4]];
    const float* bv    = (const float*)d_in[i_v96[5]];
    const float* bg    = (const float*)d_in[i_v96[6]];
    const float* bo    = (const float*)d_in[i_v96[7]];
    const float* gu    = (const float*)d_in[i_v96[8]];
    const float* betau = (const float*)d_in[i_v96[9]];

    // ---- output layout: fp32, reference return order ----
    float* outp = (float*)d_out;
    const size_t ROWS  = (size_t)BB*NN*FF;     // 786432
    const size_t WMSZ  = (size_t)BB*EE*FF;     // 12582912
    const size_t NE2   = (size_t)BB*EE*2;      // 262144
    const size_t NW    = (size_t)BB*EE;        // 131072
    float* out_un    = outp;
    float* out_wm    = outp + ROWS;
    float* out_edges = outp + ROWS + WMSZ;
    float* out_ew    = outp + ROWS + WMSZ + NE2;
    float* out_ed    = outp + ROWS + WMSZ + NE2 + NW;

    // ---- workspace layout ----
    float* ws  = (float*)d_ws;
    float* agg = ws;
    float* qo  = ws + 1*ROWS;
    float* ko  = ws + 2*ROWS;
    float* vo  = ws + 3*ROWS;
    float* go  = ws + 4*ROWS;       // att aliases go (safe: same-thread RMW)
    float* att = go;
    int* ints      = (int*)(ws + 5*ROWS);
    int* cnt       = ints;                    // B*N
    int* rowstart  = ints + BB*NN;            // B*N
    int* cursor    = ints + 2*BB*NN;          // B*N
    int* elist     = ints + 3*BB*NN;          // B*E

    hipMemsetAsync(cnt, 0, BB*NN*sizeof(int), stream);

    // CSR build (independent of GEMM)
    hist_kernel<<<(BB*EE+255)/256, 256, 0, stream>>>(edges, cnt);
    scan_kernel<<<BB, NN, 0, stream>>>(cnt, rowstart, cursor);
    scatter_kernel<<<(BB*EE+255)/256, 256, 0, stream>>>(edges, cursor, elist);

    // edge messages (writes wm only; no atomics)
    edge_msg_kernel<<<(BB*EE)/TE, 256, 0, stream>>>(nodes, ef, edges, ew,
                                               Wm, bm, gm, betam, out_wm);
    // CSR gather -> agg
    gather_kernel<<<BB*NN, 96, 0, stream>>>(out_wm, ed, elist, rowstart, cnt, agg);

    dim3 qgrid((BB*NN)/TE, 4);
    qkvg_kernel<<<qgrid, 256, 0, stream>>>(nodes, agg, Wq, bq, Wk, bk, Wv, bv,
                                           Wg, bg, qo, ko, vo, go);
    attn_kernel<<<BB*NH*16, 256, 0, stream>>>(qo, ko, vo, go, att);
    out_kernel<<<(BB*NN)/TE, 256, 0, stream>>>(att, Wo, bo, gu, betau, out_un);

    const int npass = (int)(NE2 + NW + NE2);
    passthrough_kernel<<<(npass+255)/256, 256, 0, stream>>>(edges, ew, ed,
                                               out_edges, out_ew, out_ed);
}